// Round 2
// baseline (1577.698 us; speedup 1.0000x reference)
//
#include <hip/hip_runtime.h>
#include <cstdint>

#define Tn 200
#define En 512
#define NWG 16

// ---- embed gather for batch row 63 only ----
__global__ __launch_bounds__(128) void embed_k(const int* __restrict__ ids,
                                               const float* __restrict__ tab,
                                               float* __restrict__ x0) {
  const int t = blockIdx.x;
  const int e = threadIdx.x;
  const long id = ids[63 * Tn + t];
  const float4* src = (const float4*)(tab + (size_t)id * En);
  ((float4*)(x0 + (size_t)t * En))[e] = src[e];
}

// out[t][g] = (relu?)( A[t][:512] . W[g][:512] + bp1[g] + bp2?[g] )
__global__ __launch_bounds__(256) void gemm_rows(const float* __restrict__ A,
                                                 const float* __restrict__ W,
                                                 const float* __restrict__ bp1,
                                                 const float* __restrict__ bp2,
                                                 float* __restrict__ out,
                                                 int G, int relu) {
  __shared__ float xl[8 * 512];
  const int gr = blockIdx.x * 256 + threadIdx.x;
  const int t0 = blockIdx.y * 8;
  for (int i = threadIdx.x; i < 8 * 512; i += 256) xl[i] = A[(size_t)t0 * 512 + i];
  __syncthreads();
  const float b = bp1[gr] + (bp2 ? bp2[gr] : 0.f);
  float acc[8];
#pragma unroll
  for (int tt = 0; tt < 8; tt++) acc[tt] = b;
  const float4* wr = (const float4*)(W + (size_t)gr * 512);
  for (int k4 = 0; k4 < 128; k4++) {
    const float4 w = wr[k4];
#pragma unroll
    for (int tt = 0; tt < 8; tt++) {
      const float4 xv = *(const float4*)&xl[tt * 512 + k4 * 4];
      acc[tt] = fmaf(w.x, xv.x, fmaf(w.y, xv.y, fmaf(w.z, xv.z, fmaf(w.w, xv.w, acc[tt]))));
    }
  }
#pragma unroll
  for (int tt = 0; tt < 8; tt++) {
    float v = acc[tt];
    if (relu) v = fmaxf(v, 0.f);
    out[(size_t)(t0 + tt) * G + gr] = v;
  }
}

// ---- bidirectional LSTM recurrence, single-roundtrip exchange ----
// 16 WGs x 512 threads. WG g owns h elements [16g,16g+16) for BOTH dirs.
// Exchange: per (step,dir,element) 8B slot = (stamp<<32)|float_bits, written
// once per launch per layer; relaxed agent atomics; NO fences on the chain.
// Lane map: wave w, lane l: j=2w+(l>>5), gate=(l>>3)&3, kc=l&7 -> all 4 gates
// of an h-element reduce within one wave (shfl only, no LDS/syncthreads).
__global__ __launch_bounds__(512) void rec_k(const float* __restrict__ xp,   // [T][2048] fwd|bwd
                                             float* __restrict__ hcat,       // [T][512] fwd|bwd
                                             unsigned long long* __restrict__ ex, // [T][512] slots
                                             const float* __restrict__ whhF,
                                             const float* __restrict__ whhB,
                                             unsigned stampbase) {
  __shared__ float hFs[288], hBs[288];  // stride-36 swizzle: conflict-free b128 reads
  const int tid = threadIdx.x;
  const int g = blockIdx.x;
  const int lane = tid & 63, w = tid >> 6;
  const int jhalf = lane >> 5, gt = (lane >> 3) & 3, kc = lane & 7;
  const int j = 2 * w + jhalf;
  const int gr = gt * 256 + g * 16 + j;   // global gate row (i|f|g|o blocks of 256)

  // weight slices, pinned in VGPRs (asm keeps them from being sunk/spilled)
  float wF[32], wB[32];
  {
    const float* pF = whhF + (size_t)gr * 256 + kc * 32;
    const float* pB = whhB + (size_t)gr * 256 + kc * 32;
#pragma unroll
    for (int i = 0; i < 32; i++) { wF[i] = pF[i]; wB[i] = pB[i]; }
#pragma unroll
    for (int i = 0; i < 32; i++) {
      asm volatile("" : "+v"(wF[i]));
      asm volatile("" : "+v"(wB[i]));
    }
  }
  for (int i = tid; i < 288; i += 512) { hFs[i] = 0.f; hBs[i] = 0.f; }

  float cF = 0.f, cB = 0.f;
  float xf = 0.f, xb = 0.f;
  if (kc == 0) {
    xf = xp[gr];
    xb = xp[(size_t)(Tn - 1) * 2048 + 1024 + gr];
  }
  // consumer mapping: thread tid polls slot (dir=tid>>8, element=tid&255)
  const int ck = tid & 255;
  float* const cdst = ((tid >> 8) ? hBs : hFs) + ((ck >> 5) * 36 + (ck & 31));
  const int iscomp = ((lane & 31) == 0);
  const int shbase = lane & 32;
  const int col = g * 16 + j;
  __syncthreads();

  for (int t = 0; t < Tn; ++t) {
    // register matvec: gate += whh[row] . h
    float aF = 0.f, aB = 0.f;
    const float* hF = &hFs[kc * 36];
    const float* hB = &hBs[kc * 36];
#pragma unroll
    for (int i = 0; i < 32; i++) {
      aF = fmaf(wF[i], hF[i], aF);
      aB = fmaf(wB[i], hB[i], aB);
    }
    aF += __shfl_xor(aF, 1); aB += __shfl_xor(aB, 1);
    aF += __shfl_xor(aF, 2); aB += __shfl_xor(aB, 2);
    aF += __shfl_xor(aF, 4); aB += __shfl_xor(aB, 4);
    if (kc == 0) { aF += xf; aB += xb; }
    // gather the 4 gate sums of this wave's two h-elements to lanes 0 / 32
    const float i_F = __shfl(aF, shbase + 0), f_F = __shfl(aF, shbase + 8),
                g_F = __shfl(aF, shbase + 16), o_F = __shfl(aF, shbase + 24);
    const float i_B = __shfl(aB, shbase + 0), f_B = __shfl(aB, shbase + 8),
                g_B = __shfl(aB, shbase + 16), o_B = __shfl(aB, shbase + 24);
    if (iscomp) {
      float iv = 1.f / (1.f + __expf(-i_F));
      float fv = 1.f / (1.f + __expf(-f_F));
      float gv = 1.f - 2.f / (1.f + __expf(2.f * g_F));
      float ov = 1.f / (1.f + __expf(-o_F));
      cF = fv * cF + iv * gv;
      const float hvF = ov * (1.f - 2.f / (1.f + __expf(2.f * cF)));
      iv = 1.f / (1.f + __expf(-i_B));
      fv = 1.f / (1.f + __expf(-f_B));
      gv = 1.f - 2.f / (1.f + __expf(2.f * g_B));
      ov = 1.f / (1.f + __expf(-o_B));
      cB = fv * cB + iv * gv;
      const float hvB = ov * (1.f - 2.f / (1.f + __expf(2.f * cB)));
      const unsigned long long st = (unsigned long long)(stampbase + t + 1) << 32;
      __hip_atomic_store(&ex[(size_t)t * 512 + col], st | __float_as_uint(hvF),
                         __ATOMIC_RELAXED, __HIP_MEMORY_SCOPE_AGENT);
      __hip_atomic_store(&ex[(size_t)t * 512 + 256 + col], st | __float_as_uint(hvB),
                         __ATOMIC_RELAXED, __HIP_MEMORY_SCOPE_AGENT);
      hcat[(size_t)t * 512 + col] = hvF;                    // fwd, time t
      hcat[(size_t)(Tn - 1 - t) * 512 + 256 + col] = hvB;   // bwd, reversed time
    }
    __syncthreads();  // all matvec LDS reads of h(t-1) complete
    if (t + 1 < Tn) {
      if (kc == 0) {  // prefetch next xproj during the poll
        xf = xp[(size_t)(t + 1) * 2048 + gr];
        xb = xp[(size_t)(Tn - 2 - t) * 2048 + 1024 + gr];
      }
      // poll: the data rides in the same 8B word as the stamp -> 1 round trip
      const unsigned long long* slot = &ex[(size_t)t * 512 + tid];
      const unsigned tgt = stampbase + (unsigned)t + 1u;
      unsigned long long v;
      int gd = 0;
      do {
        v = __hip_atomic_load(slot, __ATOMIC_RELAXED, __HIP_MEMORY_SCOPE_AGENT);
      } while ((unsigned)(v >> 32) != tgt && ++gd < (1 << 20));
      *cdst = __uint_as_float((unsigned)v);
      __syncthreads();  // h(t) staged for everyone
    }
  }
}

// ---- final 1024->7 matmul + softmax per timestep ----
__global__ __launch_bounds__(64) void mlp2_k(const float* __restrict__ h1,
                                             const float* __restrict__ w2,
                                             const float* __restrict__ b2,
                                             float* __restrict__ out) {
  __shared__ float hrow[1024];
  __shared__ float lg[8];
  const int t = blockIdx.x, tid = threadIdx.x;
  for (int i = tid; i < 1024; i += 64) hrow[i] = h1[(size_t)t * 1024 + i];
  __syncthreads();
  const int o = tid >> 3, kc = tid & 7;
  float acc = 0.f;
  if (o < 7) {
    const float* wv = w2 + (size_t)o * 1024 + kc * 128;
    const float* h = &hrow[kc * 128];
    for (int jj = 0; jj < 128; jj++) acc = fmaf(wv[jj], h[jj], acc);
  }
#pragma unroll
  for (int off = 1; off < 8; off <<= 1) acc += __shfl_xor(acc, off);
  if (o < 7 && kc == 0) lg[o] = acc + b2[o];
  __syncthreads();
  if (tid == 0) {
    float mx = -1e30f;
#pragma unroll
    for (int i = 0; i < 7; i++) mx = fmaxf(mx, lg[i]);
    float e[7];
    float s = 0.f;
#pragma unroll
    for (int i = 0; i < 7; i++) { e[i] = __expf(lg[i] - mx); s += e[i]; }
    const float inv = 1.f / s;
#pragma unroll
    for (int i = 0; i < 7; i++) out[t * 7 + i] = e[i] * inv;
  }
}

extern "C" void kernel_launch(void* const* d_in, const int* in_sizes, int n_in,
                              void* d_out, int out_size, void* d_ws, size_t ws_size,
                              hipStream_t stream) {
  const int* ids = (const int*)d_in[0];
  const float* tab = (const float*)d_in[1];
  const float* wih = (const float*)d_in[2];   // (2,2,1024,512)
  const float* whh = (const float*)d_in[3];   // (2,2,1024,256)
  const float* bih = (const float*)d_in[4];   // (2,2,1024)
  const float* bhh = (const float*)d_in[5];
  const float* w1 = (const float*)d_in[6];    // (1024,512)
  const float* b1 = (const float*)d_in[7];
  const float* w2 = (const float*)d_in[8];    // (7,1024)
  const float* b2 = (const float*)d_in[9];
  float* out = (float*)d_out;                 // (200,7) f32
  float* ws = (float*)d_ws;

  float* x0 = ws;                     // 200*512
  float* xp = ws + 102400;            // 200*2048 (reused both layers)
  float* h0 = ws + 512000;            // 200*512
  float* h1 = ws + 614400;            // 200*512
  float* hm = ws + 716800;            // 200*1024
  unsigned long long* ex = (unsigned long long*)(ws + 921600);  // 200*512 8B slots

  // clear stamps from the previous replay (per-t slots are write-once within a launch)
  hipMemsetAsync(ex, 0, (size_t)Tn * 512 * 8, stream);
  embed_k<<<Tn, 128, 0, stream>>>(ids, tab, x0);
  // layer 0
  gemm_rows<<<dim3(8, 25), 256, 0, stream>>>(x0, wih, bih, bhh, xp, 2048, 0);
  rec_k<<<NWG, 512, 0, stream>>>(xp, h0, ex, whh, whh + 262144, 0u);
  // layer 1 (shared ex buffer, disjoint stamp base)
  gemm_rows<<<dim3(8, 25), 256, 0, stream>>>(h0, wih + 1048576, bih + 2048, bhh + 2048, xp, 2048, 0);
  rec_k<<<NWG, 512, 0, stream>>>(xp, h1, ex, whh + 524288, whh + 786432, 1000000u);
  // MLP
  gemm_rows<<<dim3(4, 25), 256, 0, stream>>>(h1, w1, b1, nullptr, hm, 1024, 1);
  mlp2_k<<<Tn, 64, 0, stream>>>(hm, w2, b2, out);
}

// Round 3
// 812.841 us; speedup vs baseline: 1.9410x; 1.9410x over previous
//
#include <hip/hip_runtime.h>
#include <cstdint>

#define Tn 200
#define En 512

// ---- embed gather for batch row 63 only ----
__global__ __launch_bounds__(128) void embed_k(const int* __restrict__ ids,
                                               const float* __restrict__ tab,
                                               float* __restrict__ x0) {
  const int t = blockIdx.x;
  const int e = threadIdx.x;
  const long id = ids[63 * Tn + t];
  const float4* src = (const float4*)(tab + (size_t)id * En);
  ((float4*)(x0 + (size_t)t * En))[e] = src[e];
}

// out[t][g] = (relu?)( A[t][:512] . W[g][:512] + bp1[g] + bp2?[g] )
__global__ __launch_bounds__(256) void gemm_rows(const float* __restrict__ A,
                                                 const float* __restrict__ W,
                                                 const float* __restrict__ bp1,
                                                 const float* __restrict__ bp2,
                                                 float* __restrict__ out,
                                                 int G, int relu) {
  __shared__ float xl[8 * 512];
  const int gr = blockIdx.x * 256 + threadIdx.x;
  const int t0 = blockIdx.y * 8;
  for (int i = threadIdx.x; i < 8 * 512; i += 256) xl[i] = A[(size_t)t0 * 512 + i];
  __syncthreads();
  const float b = bp1[gr] + (bp2 ? bp2[gr] : 0.f);
  float acc[8];
#pragma unroll
  for (int tt = 0; tt < 8; tt++) acc[tt] = b;
  const float4* wr = (const float4*)(W + (size_t)gr * 512);
  for (int k4 = 0; k4 < 128; k4++) {
    const float4 w = wr[k4];
#pragma unroll
    for (int tt = 0; tt < 8; tt++) {
      const float4 xv = *(const float4*)&xl[tt * 512 + k4 * 4];
      acc[tt] = fmaf(w.x, xv.x, fmaf(w.y, xv.y, fmaf(w.z, xv.z, fmaf(w.w, xv.w, acc[tt]))));
    }
  }
#pragma unroll
  for (int tt = 0; tt < 8; tt++) {
    float v = acc[tt];
    if (relu) v = fmaxf(v, 0.f);
    out[(size_t)(t0 + tt) * G + gr] = v;
  }
}

// ---- bidirectional LSTM recurrence ----
// 16 WGs: blocks 0-7 = fwd domain, 8-15 = bwd domain (independent syncs).
// WG owns 32 h-elements of ONE direction; whh slice (128 rows x 256) in
// registers: 64 floats/thread. launch_bounds(512,2) caps occupancy at one
// 512-thread WG per CU -> 256 VGPR budget so the weights actually stay
// resident (R1 failure: VGPR_Count=56 => spilled weights re-streamed/step).
// Exchange: per (step,dir,elem) 8B slot = (stamp<<32)|float_bits, relaxed
// agent atomics, write-once per launch; consumer's poll IS the data load.
// Thread map: j=tid>>4 (elem), gt=(tid>>2)&3 (gate), kc=tid&3 (k-chunk of 64).
__global__ __launch_bounds__(512, 2) void rec_k(const float* __restrict__ xp,   // [T][2048] fwd|bwd
                                                float* __restrict__ hcat,       // [T][512]
                                                unsigned long long* __restrict__ ex, // [T][512]
                                                const float* __restrict__ whh,  // dir-major, 2*1024*256
                                                unsigned stampbase) {
  __shared__ float hs[4 * 68];  // stride-68 swizzle: kc chunks hit distinct banks
  const int tid = threadIdx.x;
  const int gb = blockIdx.x;
  const int dir = gb >> 3, wg = gb & 7;
  const int lane = tid & 63;
  const int j = tid >> 4, gt = (tid >> 2) & 3, kc = tid & 3;
  const int he = wg * 32 + j;         // global h element in [0,256)
  const int gr = gt * 256 + he;       // gate row (i|f|g|o blocks of 256)
  const float* whhD = whh + (size_t)dir * 262144;
  const float* xpD = xp + dir * 1024;

  float wv[64];
  {
    const float* p = whhD + (size_t)gr * 256 + kc * 64;
#pragma unroll
    for (int i = 0; i < 64; i++) wv[i] = p[i];
#pragma unroll
    for (int i = 0; i < 64; i++) asm volatile("" : "+v"(wv[i]));
  }
  for (int i = tid; i < 4 * 68; i += 512) hs[i] = 0.f;
  float c = 0.f;
  float xv = 0.f;
  if (kc == 0) xv = xpD[(size_t)(dir ? (Tn - 1) : 0) * 2048 + gr];
  const int isprod = ((tid & 15) == 0);
  const int base = lane & 48;
  __syncthreads();

  for (int t = 0; t < Tn; ++t) {
    // register matvec: row (j,gt), k-chunk kc
    float a = 0.f;
    const float* h = &hs[kc * 68];
#pragma unroll
    for (int i = 0; i < 64; i++) a = fmaf(wv[i], h[i], a);
    a += __shfl_xor(a, 1);
    a += __shfl_xor(a, 2);
    if (kc == 0) a += xv;  // xproj(+biases) folded in by gemm_rows
    // gather the 4 gate sums of elem j to its base lane
    const float gi = __shfl(a, base + 0);
    const float gf = __shfl(a, base + 4);
    const float gg = __shfl(a, base + 8);
    const float go = __shfl(a, base + 12);
    if (isprod) {
      const float iv = 1.f / (1.f + __expf(-gi));
      const float fv = 1.f / (1.f + __expf(-gf));
      const float gv = 1.f - 2.f / (1.f + __expf(2.f * gg));
      const float ov = 1.f / (1.f + __expf(-go));
      c = fv * c + iv * gv;
      const float hv = ov * (1.f - 2.f / (1.f + __expf(2.f * c)));
      const int rowt = dir ? (Tn - 1 - t) : t;
      hcat[(size_t)rowt * 512 + dir * 256 + he] = hv;
      __hip_atomic_store(&ex[(size_t)t * 512 + dir * 256 + he],
                         ((unsigned long long)(stampbase + t + 1) << 32) | __float_as_uint(hv),
                         __ATOMIC_RELAXED, __HIP_MEMORY_SCOPE_AGENT);
    }
    __syncthreads();  // all matvec reads of h(t-1) done before hs is overwritten
    if (t + 1 < Tn) {
      if (kc == 0)  // prefetch next step's xproj during the poll
        xv = xpD[(size_t)(dir ? (Tn - 2 - t) : (t + 1)) * 2048 + gr];
      if (tid < 256) {  // one poller per h element of OUR direction only
        const unsigned long long* slot = &ex[(size_t)t * 512 + dir * 256 + tid];
        const unsigned tgt = stampbase + (unsigned)t + 1u;
        unsigned long long v;
        int gd = 0;
        do {
          v = __hip_atomic_load(slot, __ATOMIC_RELAXED, __HIP_MEMORY_SCOPE_AGENT);
        } while ((unsigned)(v >> 32) != tgt && ++gd < (1 << 20));
        hs[(tid >> 6) * 68 + (tid & 63)] = __uint_as_float((unsigned)v);
      }
      __syncthreads();  // h(t) staged for everyone
    }
  }
}

// ---- final 1024->7 matmul + softmax per timestep ----
__global__ __launch_bounds__(64) void mlp2_k(const float* __restrict__ h1,
                                             const float* __restrict__ w2,
                                             const float* __restrict__ b2,
                                             float* __restrict__ out) {
  __shared__ float hrow[1024];
  __shared__ float lg[8];
  const int t = blockIdx.x, tid = threadIdx.x;
  for (int i = tid; i < 1024; i += 64) hrow[i] = h1[(size_t)t * 1024 + i];
  __syncthreads();
  const int o = tid >> 3, kc = tid & 7;
  float acc = 0.f;
  if (o < 7) {
    const float* wv = w2 + (size_t)o * 1024 + kc * 128;
    const float* h = &hrow[kc * 128];
    for (int jj = 0; jj < 128; jj++) acc = fmaf(wv[jj], h[jj], acc);
  }
#pragma unroll
  for (int off = 1; off < 8; off <<= 1) acc += __shfl_xor(acc, off);
  if (o < 7 && kc == 0) lg[o] = acc + b2[o];
  __syncthreads();
  if (tid == 0) {
    float mx = -1e30f;
#pragma unroll
    for (int i = 0; i < 7; i++) mx = fmaxf(mx, lg[i]);
    float e[7];
    float s = 0.f;
#pragma unroll
    for (int i = 0; i < 7; i++) { e[i] = __expf(lg[i] - mx); s += e[i]; }
    const float inv = 1.f / s;
#pragma unroll
    for (int i = 0; i < 7; i++) out[t * 7 + i] = e[i] * inv;
  }
}

extern "C" void kernel_launch(void* const* d_in, const int* in_sizes, int n_in,
                              void* d_out, int out_size, void* d_ws, size_t ws_size,
                              hipStream_t stream) {
  const int* ids = (const int*)d_in[0];
  const float* tab = (const float*)d_in[1];
  const float* wih = (const float*)d_in[2];   // (2,2,1024,512)
  const float* whh = (const float*)d_in[3];   // (2,2,1024,256)
  const float* bih = (const float*)d_in[4];   // (2,2,1024)
  const float* bhh = (const float*)d_in[5];
  const float* w1 = (const float*)d_in[6];    // (1024,512)
  const float* b1 = (const float*)d_in[7];
  const float* w2 = (const float*)d_in[8];    // (7,1024)
  const float* b2 = (const float*)d_in[9];
  float* out = (float*)d_out;                 // (200,7) f32
  float* ws = (float*)d_ws;

  float* x0 = ws;                     // 200*512
  float* xp = ws + 102400;            // 200*2048 (reused both layers)
  float* h0 = ws + 512000;            // 200*512
  float* h1 = ws + 614400;            // 200*512
  float* hm = ws + 716800;            // 200*1024
  unsigned long long* ex = (unsigned long long*)(ws + 921600);  // 200*512 8B slots

  // clear stamps from previous replay (slots are write-once within a launch)
  hipMemsetAsync(ex, 0, (size_t)Tn * 512 * 8, stream);
  embed_k<<<Tn, 128, 0, stream>>>(ids, tab, x0);
  // layer 0
  gemm_rows<<<dim3(8, 25), 256, 0, stream>>>(x0, wih, bih, bhh, xp, 2048, 0);
  rec_k<<<16, 512, 0, stream>>>(xp, h0, ex, whh, 0u);
  // layer 1 (shared ex buffer, disjoint stamp base)
  gemm_rows<<<dim3(8, 25), 256, 0, stream>>>(h0, wih + 1048576, bih + 2048, bhh + 2048, xp, 2048, 0);
  rec_k<<<16, 512, 0, stream>>>(xp, h1, ex, whh + 524288, 1000000u);
  // MLP
  gemm_rows<<<dim3(4, 25), 256, 0, stream>>>(h1, w1, b1, nullptr, hm, 1024, 1);
  mlp2_k<<<Tn, 64, 0, stream>>>(hm, w2, b2, out);
}

// Round 4
// 800.423 us; speedup vs baseline: 1.9711x; 1.0155x over previous
//
#include <hip/hip_runtime.h>
#include <cstdint>

#define Tn 200
#define En 512

// ---- embed gather for batch row 63 only ----
__global__ __launch_bounds__(128) void embed_k(const int* __restrict__ ids,
                                               const float* __restrict__ tab,
                                               float* __restrict__ x0) {
  const int t = blockIdx.x;
  const int e = threadIdx.x;
  const long id = ids[63 * Tn + t];
  const float4* src = (const float4*)(tab + (size_t)id * En);
  ((float4*)(x0 + (size_t)t * En))[e] = src[e];
}

// out[t][g] = (relu?)( A[t][:512] . W[g][:512] + bp1[g] + bp2?[g] )
__global__ __launch_bounds__(256) void gemm_rows(const float* __restrict__ A,
                                                 const float* __restrict__ W,
                                                 const float* __restrict__ bp1,
                                                 const float* __restrict__ bp2,
                                                 float* __restrict__ out,
                                                 int G, int relu) {
  __shared__ float xl[8 * 512];
  const int gr = blockIdx.x * 256 + threadIdx.x;
  const int t0 = blockIdx.y * 8;
  for (int i = threadIdx.x; i < 8 * 512; i += 256) xl[i] = A[(size_t)t0 * 512 + i];
  __syncthreads();
  const float b = bp1[gr] + (bp2 ? bp2[gr] : 0.f);
  float acc[8];
#pragma unroll
  for (int tt = 0; tt < 8; tt++) acc[tt] = b;
  const float4* wr = (const float4*)(W + (size_t)gr * 512);
  for (int k4 = 0; k4 < 128; k4++) {
    const float4 w = wr[k4];
#pragma unroll
    for (int tt = 0; tt < 8; tt++) {
      const float4 xv = *(const float4*)&xl[tt * 512 + k4 * 4];
      acc[tt] = fmaf(w.x, xv.x, fmaf(w.y, xv.y, fmaf(w.z, xv.z, fmaf(w.w, xv.w, acc[tt]))));
    }
  }
#pragma unroll
  for (int tt = 0; tt < 8; tt++) {
    float v = acc[tt];
    if (relu) v = fmaxf(v, 0.f);
    out[(size_t)(t0 + tt) * G + gr] = v;
  }
}

// ---- bidirectional LSTM recurrence ----
// 32 WGs x 512 threads: blocks 0-15 fwd, 16-31 bwd (independent sync domains).
// WG owns 16 h-elements of one direction = 64 gate rows; each thread holds a
// 32-float whh slice as 8 NAMED float4s (no array -> guaranteed SROA, ~80 VGPR,
// well under the 256 budget from launch_bounds(512,2): R3 failure was a
// 64-float array spilling to scratch, VGPR_Count=48).
// Thread map: row=tid>>3 (elem*4+gate), kc=tid&7 (32-float k-chunk).
// h staged in LDS stride 36 -> ds_read_b128 conflict-free (banks 4kc+4i tile).
// Exchange: 8B slot = (stamp<<32)|float_bits, relaxed agent atomics.
__global__ __launch_bounds__(512, 2) void rec_k(const float* __restrict__ xp,   // [T][2048] fwd|bwd
                                                float* __restrict__ hcat,       // [T][512]
                                                unsigned long long* __restrict__ ex, // [T][512]
                                                const float* __restrict__ whh,  // dir-major 2*1024*256
                                                unsigned stampbase) {
  __shared__ float hs[8 * 36];
  const int tid = threadIdx.x;
  const int gb = blockIdx.x;
  const int dir = gb >> 4, wg = gb & 15;
  const int lane = tid & 63;
  const int row = tid >> 3, kc = tid & 7;
  const int elem = row >> 2, gate = row & 3;
  const int he = wg * 16 + elem;        // global h element [0,256)
  const int gr = gate * 256 + he;       // gate row (i|f|g|o blocks of 256)
  const float* whhD = whh + (size_t)dir * 262144;
  const float* xpD = xp + dir * 1024;

  float4 q0, q1, q2, q3, q4, q5, q6, q7;
  {
    const float4* p = (const float4*)(whhD + (size_t)gr * 256 + kc * 32);
    q0 = p[0]; q1 = p[1]; q2 = p[2]; q3 = p[3];
    q4 = p[4]; q5 = p[5]; q6 = p[6]; q7 = p[7];
    asm volatile("" : "+v"(q0.x), "+v"(q0.y), "+v"(q0.z), "+v"(q0.w));
    asm volatile("" : "+v"(q1.x), "+v"(q1.y), "+v"(q1.z), "+v"(q1.w));
    asm volatile("" : "+v"(q2.x), "+v"(q2.y), "+v"(q2.z), "+v"(q2.w));
    asm volatile("" : "+v"(q3.x), "+v"(q3.y), "+v"(q3.z), "+v"(q3.w));
    asm volatile("" : "+v"(q4.x), "+v"(q4.y), "+v"(q4.z), "+v"(q4.w));
    asm volatile("" : "+v"(q5.x), "+v"(q5.y), "+v"(q5.z), "+v"(q5.w));
    asm volatile("" : "+v"(q6.x), "+v"(q6.y), "+v"(q6.z), "+v"(q6.w));
    asm volatile("" : "+v"(q7.x), "+v"(q7.y), "+v"(q7.z), "+v"(q7.w));
  }
  for (int i = tid; i < 8 * 36; i += 512) hs[i] = 0.f;
  float c = 0.f;
  float xv = 0.f;
  if (kc == 0) xv = xpD[(size_t)(dir ? (Tn - 1) : 0) * 2048 + gr];
  const int isprod = ((lane & 31) == 0);
  const int base = lane & 32;
  __syncthreads();

  for (int t = 0; t < Tn; ++t) {
    // register matvec, h via conflict-free b128 LDS reads
    const float4* h4 = (const float4*)&hs[kc * 36];
    const float4 h0 = h4[0], h1 = h4[1], h2 = h4[2], h3 = h4[3];
    const float4 h5 = h4[4], h6 = h4[5], h7 = h4[6], h8 = h4[7];
    float a = 0.f;
    a = fmaf(q0.x, h0.x, a); a = fmaf(q0.y, h0.y, a); a = fmaf(q0.z, h0.z, a); a = fmaf(q0.w, h0.w, a);
    a = fmaf(q1.x, h1.x, a); a = fmaf(q1.y, h1.y, a); a = fmaf(q1.z, h1.z, a); a = fmaf(q1.w, h1.w, a);
    a = fmaf(q2.x, h2.x, a); a = fmaf(q2.y, h2.y, a); a = fmaf(q2.z, h2.z, a); a = fmaf(q2.w, h2.w, a);
    a = fmaf(q3.x, h3.x, a); a = fmaf(q3.y, h3.y, a); a = fmaf(q3.z, h3.z, a); a = fmaf(q3.w, h3.w, a);
    a = fmaf(q4.x, h5.x, a); a = fmaf(q4.y, h5.y, a); a = fmaf(q4.z, h5.z, a); a = fmaf(q4.w, h5.w, a);
    a = fmaf(q5.x, h6.x, a); a = fmaf(q5.y, h6.y, a); a = fmaf(q5.z, h6.z, a); a = fmaf(q5.w, h6.w, a);
    a = fmaf(q6.x, h7.x, a); a = fmaf(q6.y, h7.y, a); a = fmaf(q6.z, h7.z, a); a = fmaf(q6.w, h7.w, a);
    a = fmaf(q7.x, h8.x, a); a = fmaf(q7.y, h8.y, a); a = fmaf(q7.z, h8.z, a); a = fmaf(q7.w, h8.w, a);
    a += __shfl_xor(a, 1);
    a += __shfl_xor(a, 2);
    a += __shfl_xor(a, 4);
    if (kc == 0) a += xv;   // xproj (+biases) folded in by gemm_rows
    // gather the 4 gate sums of this wave's two elements to lanes 0 / 32
    const float gi = __shfl(a, base + 0);
    const float gf = __shfl(a, base + 8);
    const float gg = __shfl(a, base + 16);
    const float go = __shfl(a, base + 24);
    if (isprod) {
      const float iv = 1.f / (1.f + __expf(-gi));
      const float fv = 1.f / (1.f + __expf(-gf));
      const float gv = 1.f - 2.f / (1.f + __expf(2.f * gg));
      const float ov = 1.f / (1.f + __expf(-go));
      c = fv * c + iv * gv;
      const float hv = ov * (1.f - 2.f / (1.f + __expf(2.f * c)));
      // flag word FIRST (critical path), bulk output second
      __hip_atomic_store(&ex[(size_t)t * 512 + dir * 256 + he],
                         ((unsigned long long)(stampbase + t + 1) << 32) | __float_as_uint(hv),
                         __ATOMIC_RELAXED, __HIP_MEMORY_SCOPE_AGENT);
      const int rowt = dir ? (Tn - 1 - t) : t;
      hcat[(size_t)rowt * 512 + dir * 256 + he] = hv;
    }
    __syncthreads();  // all matvec reads of h(t-1) done before hs is overwritten
    if (t + 1 < Tn) {
      if (kc == 0)  // prefetch next step's xproj during the poll
        xv = xpD[(size_t)(dir ? (Tn - 2 - t) : (t + 1)) * 2048 + gr];
      if (tid < 256) {  // one poller per h element of OUR direction
        const unsigned long long* slot = &ex[(size_t)t * 512 + dir * 256 + tid];
        const unsigned tgt = stampbase + (unsigned)t + 1u;
        unsigned long long v;
        int gd = 0;
        do {
          v = __hip_atomic_load(slot, __ATOMIC_RELAXED, __HIP_MEMORY_SCOPE_AGENT);
        } while ((unsigned)(v >> 32) != tgt && ++gd < (1 << 20));
        hs[(tid >> 5) * 36 + (tid & 31)] = __uint_as_float((unsigned)v);
      }
      __syncthreads();  // h(t) staged for everyone
    }
  }
}

// ---- final 1024->7 matmul + softmax per timestep ----
__global__ __launch_bounds__(64) void mlp2_k(const float* __restrict__ h1,
                                             const float* __restrict__ w2,
                                             const float* __restrict__ b2,
                                             float* __restrict__ out) {
  __shared__ float hrow[1024];
  __shared__ float lg[8];
  const int t = blockIdx.x, tid = threadIdx.x;
  for (int i = tid; i < 1024; i += 64) hrow[i] = h1[(size_t)t * 1024 + i];
  __syncthreads();
  const int o = tid >> 3, kc = tid & 7;
  float acc = 0.f;
  if (o < 7) {
    const float* wv = w2 + (size_t)o * 1024 + kc * 128;
    const float* h = &hrow[kc * 128];
    for (int jj = 0; jj < 128; jj++) acc = fmaf(wv[jj], h[jj], acc);
  }
#pragma unroll
  for (int off = 1; off < 8; off <<= 1) acc += __shfl_xor(acc, off);
  if (o < 7 && kc == 0) lg[o] = acc + b2[o];
  __syncthreads();
  if (tid == 0) {
    float mx = -1e30f;
#pragma unroll
    for (int i = 0; i < 7; i++) mx = fmaxf(mx, lg[i]);
    float e[7];
    float s = 0.f;
#pragma unroll
    for (int i = 0; i < 7; i++) { e[i] = __expf(lg[i] - mx); s += e[i]; }
    const float inv = 1.f / s;
#pragma unroll
    for (int i = 0; i < 7; i++) out[t * 7 + i] = e[i] * inv;
  }
}

extern "C" void kernel_launch(void* const* d_in, const int* in_sizes, int n_in,
                              void* d_out, int out_size, void* d_ws, size_t ws_size,
                              hipStream_t stream) {
  const int* ids = (const int*)d_in[0];
  const float* tab = (const float*)d_in[1];
  const float* wih = (const float*)d_in[2];   // (2,2,1024,512)
  const float* whh = (const float*)d_in[3];   // (2,2,1024,256)
  const float* bih = (const float*)d_in[4];   // (2,2,1024)
  const float* bhh = (const float*)d_in[5];
  const float* w1 = (const float*)d_in[6];    // (1024,512)
  const float* b1 = (const float*)d_in[7];
  const float* w2 = (const float*)d_in[8];    // (7,1024)
  const float* b2 = (const float*)d_in[9];
  float* out = (float*)d_out;                 // (200,7) f32
  float* ws = (float*)d_ws;

  float* x0 = ws;                     // 200*512
  float* xp = ws + 102400;            // 200*2048 (reused both layers)
  float* h0 = ws + 512000;            // 200*512
  float* h1 = ws + 614400;            // 200*512
  float* hm = ws + 716800;            // 200*1024
  unsigned long long* ex = (unsigned long long*)(ws + 921600);  // 200*512 8B slots

  // clear stamps from previous replay (slots are write-once within a launch)
  hipMemsetAsync(ex, 0, (size_t)Tn * 512 * 8, stream);
  embed_k<<<Tn, 128, 0, stream>>>(ids, tab, x0);
  // layer 0
  gemm_rows<<<dim3(8, 25), 256, 0, stream>>>(x0, wih, bih, bhh, xp, 2048, 0);
  rec_k<<<32, 512, 0, stream>>>(xp, h0, ex, whh, 0u);
  // layer 1 (shared ex buffer, disjoint stamp base)
  gemm_rows<<<dim3(8, 25), 256, 0, stream>>>(h0, wih + 1048576, bih + 2048, bhh + 2048, xp, 2048, 0);
  rec_k<<<32, 512, 0, stream>>>(xp, h1, ex, whh + 524288, 1000000u);
  // MLP
  gemm_rows<<<dim3(4, 25), 256, 0, stream>>>(h1, w1, b1, nullptr, hm, 1024, 1);
  mlp2_k<<<Tn, 64, 0, stream>>>(hm, w2, b2, out);
}